// Round 5
// baseline (3155.048 us; speedup 1.0000x reference)
//
#include <hip/hip_runtime.h>
#include <hip/hip_bf16.h>

// ConvGRU via split-bf16 MFMA implicit GEMM, LDS tap staging, phase-split
// K-loop. Tile = 2 rows x 32 cols per WG (wave = half-row, 1 m-tile) ->
// grid 2048 WGs (8/CU), LDS 18.5KB (8 WG/CU), acc 16 VGPR -> 32 waves/CU.
// States packed u32 = (hi_bf16<<16)|lo_bf16, NHWC, 1-px halo:
//   Sp[B][130][130][64] (ch0-31=h0, ch32-63=h1), RHp[B][130][130][32].
// Precision: a*b ~= a_hi*b_hi + a_hi*b_lo + a_lo*b_hi (3 MFMAs), fp32 acc.

#define HH 128
#define PH 130
#define HW 16384
#define BB 8
#define TT 16

typedef __bf16 bf16x8 __attribute__((ext_vector_type(8)));
typedef float f32x4 __attribute__((ext_vector_type(4)));
typedef unsigned int u32x4 __attribute__((ext_vector_type(4)));

#define SLOT_SZ (4 * 4 * 35 * 8)   // 4480 ushorts = 8960 B (col stride 35: pad)

__device__ __forceinline__ unsigned short bf16_rne(float x){
    unsigned u = __float_as_uint(x);
    return (unsigned short)((u + 0x7FFFu + ((u >> 16) & 1u)) >> 16);
}
__device__ __forceinline__ float b2f(unsigned short h){
    return __uint_as_float(((unsigned)h) << 16);
}
__device__ __forceinline__ __bf16 us2bf(unsigned short u){
    return __builtin_bit_cast(__bf16, u);
}
__device__ __forceinline__ void split2(float x, unsigned short& hi, unsigned short& lo){
    hi = bf16_rne(x);
    lo = bf16_rne(x - b2f(hi));
}
__device__ __forceinline__ unsigned packsplit(float x){
    unsigned short hi, lo; split2(x, hi, lo);
    return ((unsigned)hi << 16) | lo;
}
__device__ __forceinline__ float unpack2f(unsigned w){
    return b2f((unsigned short)(w >> 16)) + b2f((unsigned short)(w & 0xffffu));
}
__device__ __forceinline__ bf16x8 ld_frag(const unsigned short* p){
    u32x4 v = *(const u32x4*)p;
    return __builtin_bit_cast(bf16x8, v);
}
__device__ __forceinline__ bf16x8 lds_frag(const unsigned short* slot, int q, int row, int col){
    u32x4 v = *(const u32x4*)(slot + ((q * 4 + row) * 35 + col) * 8);
    return __builtin_bit_cast(bf16x8, v);
}
__device__ __forceinline__ float sigmoid_f(float a){ return 1.0f / (1.0f + __expf(-a)); }
__device__ __forceinline__ float tanh_f(float a){ float e2 = __expf(2.0f * a); return 1.0f - 2.0f / (e2 + 1.0f); }

// stage one packed 32-ch plane tile (4 rows x 34 cols) into hi/lo LDS slots.
// LDS slot layout: [qblk 4][row 4][col 35(pad)][8ch].
__device__ __forceinline__ void stage_pair(unsigned short* hs, unsigned short* ls,
    const unsigned int* __restrict__ g, int pch, int choff, int pbase)
{
    for (int c = threadIdx.x; c < 544; c += 256) {
        int qq = c & 3;
        int p  = c >> 2;
        int r  = p / 34, cc = p - r * 34;
        const unsigned int* ga = g + (long)(pbase + r * PH + cc) * pch + choff + qq * 8;
        u32x4 w0 = *(const u32x4*)ga;
        u32x4 w1 = *(const u32x4*)(ga + 4);
        u32x4 hv, lv;
        hv[0] = (w0[0] >> 16) | (w0[1] & 0xffff0000u);
        hv[1] = (w0[2] >> 16) | (w0[3] & 0xffff0000u);
        hv[2] = (w1[0] >> 16) | (w1[1] & 0xffff0000u);
        hv[3] = (w1[2] >> 16) | (w1[3] & 0xffff0000u);
        lv[0] = (w0[0] & 0xffffu) | (w0[1] << 16);
        lv[1] = (w0[2] & 0xffffu) | (w0[3] << 16);
        lv[2] = (w1[0] & 0xffffu) | (w1[1] << 16);
        lv[3] = (w1[2] & 0xffffu) | (w1[3] << 16);
        int la = ((qq * 4 + r) * 35 + cc) * 8;
        *(u32x4*)(hs + la) = hv;
        *(u32x4*)(ls + la) = lv;
    }
}

// stage raw x (unpadded fp32 image) tile with bounds-check into LDS
__device__ __forceinline__ void stage_x(float* xt, const float* __restrict__ x,
                                        int row0p, int col0p)
{
    for (int p = threadIdx.x; p < 136; p += 256) {
        int r = p / 34, cc = p - r * 34;
        int ir = row0p - 1 + r, ic = col0p - 1 + cc;
        float v = 0.0f;
        if (ir >= 0 && ir < HH && ic >= 0 && ic < HH) v = x[ir * HH + ic];
        xt[r * 35 + cc] = v;
    }
}

// ---- weight prep: [cout][cin_tot][9] fp32 -> [step][cout][32] bf16 hi/lo ----
__global__ void prep_w(const float* __restrict__ w, unsigned short* __restrict__ whi,
                       unsigned short* __restrict__ wlo, int CO, int CIT, int NSTEP, int xmode)
{
    int idx = blockIdx.x * 256 + threadIdx.x;
    int total = NSTEP * CO * 32;
    if (idx >= total) return;
    int kk = idx & 31;
    int t  = idx >> 5;
    int co = t % CO;
    int s  = t / CO;
    float v = 0.0f;
    if (xmode && s == NSTEP - 1) {
        if (kk < 9) v = w[(co * CIT + 0) * 9 + kk];
    } else {
        int tap = s % 9;
        int cin = (s / 9) * 32 + kk + (xmode ? 1 : 0);
        v = w[(co * CIT + cin) * 9 + tap];
    }
    unsigned short hi, lo; split2(v, hi, lo);
    whi[idx] = hi; wlo[idx] = lo;
}

// ---- fused conv+epilogue. CONV: 0=gates0 1=cand0 2=gates1 3=cand1 ----
// WG = 256 thr (4 waves), tile 2 rows x 32 cols; wave = half-row, 1 m-tile.
template<int CONV>
__global__ __launch_bounds__(256, 8)
void conv_mfma(unsigned int* __restrict__ Sp, unsigned int* __restrict__ RHp,
               const float* __restrict__ xraw, long xbs,
               const unsigned short* __restrict__ Whi, const unsigned short* __restrict__ Wlo,
               const float* __restrict__ bias, float* __restrict__ zbuf)
{
    constexpr bool GATES = (CONV == 0 || CONV == 2);
    constexpr bool XMODE = (CONV < 2);
    constexpr int CO = GATES ? 64 : 32;
    constexpr int NG = CO / 16;
    constexpr int HB = XMODE ? 0 : 32;   // h channel base in Sp (h0 vs h1)

    __shared__ __align__(16) unsigned short sh[SLOT_SZ], sl[SLOT_SZ];
    __shared__ float xt[XMODE ? 140 : 1];

    const int b   = blockIdx.y;
    const int tc  = blockIdx.x & 3;     // 0..3   (32-col tiles)
    const int tr  = blockIdx.x >> 2;    // 0..63  (2-row tiles)
    const int row0p = tr * 2;           // halo origin, padded coords
    const int col0p = tc * 32;
    const int pbase = (b * PH + row0p) * PH + col0p;

    // phase A staging: conv0/2/3 -> S h0-half; conv1 -> RH
    if (CONV == 1) stage_pair(sh, sl, RHp, 32, 0, pbase);
    else           stage_pair(sh, sl, Sp, 64, 0, pbase);
    if (XMODE) stage_x(xt, xraw + (long)b * xbs, row0p, col0p);
    __syncthreads();

    const int wv   = threadIdx.x >> 6;
    const int rw   = wv >> 1;           // row within tile (0..1)
    const int m16  = (wv & 1) << 4;     // col-half base (0 or 16)
    const int lane = threadIdx.x & 63;
    const int m    = lane & 15, q = lane >> 4;

    f32x4 acc[NG];
#pragma unroll
    for (int ng = 0; ng < NG; ++ng) {
        float bv = bias[ng * 16 + m];
        acc[ng] = f32x4{bv, bv, bv, bv};
    }

#define KSTEP(S, TAP)                                                           \
    {                                                                           \
        bf16x8 Ahi, Alo, Bh[NG], Bl[NG];                                        \
        const int rr = rw + (TAP) / 3, csh = (TAP) % 3;                         \
        Ahi = lds_frag(sh, q, rr, m16 + m + csh);                               \
        Alo = lds_frag(sl, q, rr, m16 + m + csh);                               \
        _Pragma("unroll")                                                       \
        for (int ng = 0; ng < NG; ++ng) {                                       \
            int widx = ((S) * CO + ng * 16 + m) * 32 + q * 8;                   \
            Bh[ng] = ld_frag(Whi + widx);                                       \
            Bl[ng] = ld_frag(Wlo + widx);                                       \
        }                                                                       \
        _Pragma("unroll")                                                       \
        for (int ng = 0; ng < NG; ++ng) {                                       \
            acc[ng] = __builtin_amdgcn_mfma_f32_16x16x32_bf16(Ahi, Bh[ng], acc[ng], 0, 0, 0); \
            acc[ng] = __builtin_amdgcn_mfma_f32_16x16x32_bf16(Ahi, Bl[ng], acc[ng], 0, 0, 0); \
            acc[ng] = __builtin_amdgcn_mfma_f32_16x16x32_bf16(Alo, Bh[ng], acc[ng], 0, 0, 0); \
        }                                                                       \
    }

#pragma unroll
    for (int s = 0; s < 9; ++s) KSTEP(s, s)

    if (XMODE) {
        // im2col x step (s=9): A[m][k] = x tap k (k<9), else 0
        bf16x8 Ahi, Alo, Bh[NG], Bl[NG];
        {
            bf16x8 vh, vl;
#pragma unroll
            for (int j = 0; j < 8; ++j) {
                int k = q * 8 + j;
                float v = 0.0f;
                if (k < 9) v = xt[(rw + k / 3) * 35 + (m16 + m + k % 3)];
                unsigned short hi, lo; split2(v, hi, lo);
                vh[j] = us2bf(hi); vl[j] = us2bf(lo);
            }
            Ahi = vh; Alo = vl;
        }
#pragma unroll
        for (int ng = 0; ng < NG; ++ng) {
            int widx = (9 * CO + ng * 16 + m) * 32 + q * 8;
            Bh[ng] = ld_frag(Whi + widx);
            Bl[ng] = ld_frag(Wlo + widx);
        }
#pragma unroll
        for (int ng = 0; ng < NG; ++ng) {
            acc[ng] = __builtin_amdgcn_mfma_f32_16x16x32_bf16(Ahi, Bh[ng], acc[ng], 0, 0, 0);
            acc[ng] = __builtin_amdgcn_mfma_f32_16x16x32_bf16(Ahi, Bl[ng], acc[ng], 0, 0, 0);
            acc[ng] = __builtin_amdgcn_mfma_f32_16x16x32_bf16(Alo, Bh[ng], acc[ng], 0, 0, 0);
        }
    } else {
        // phase B: conv2 -> S h1-half; conv3 -> RH. Re-stage same slots.
        __syncthreads();
        if (CONV == 2) stage_pair(sh, sl, Sp, 64, 32, pbase);
        else           stage_pair(sh, sl, RHp, 32, 0, pbase);
        __syncthreads();
#pragma unroll
        for (int s = 9; s < 18; ++s) KSTEP(s, s - 9)
    }

    // ---- epilogue. C layout: col(n)=lane&15, row(pixel)=q*4+reg ----
    const int prow = row0p + rw;   // image row of this wave's pixels
    if (GATES) {
        // h for r*h comes from LDS: conv0 -> h0 (phase A), conv2 -> h1 (phase B)
#pragma unroll
        for (int ng = 0; ng < NG / 2; ++ng)
#pragma unroll
            for (int rg = 0; rg < 4; ++rg) {
                int lcol = m16 + q * 4 + rg;                   // 0..31
                int psp  = (b * PH + prow + 1) * PH + (col0p + 1 + lcol);
                int pxp  = (b * HH + prow) * HH + (col0p + lcol);
                int n    = ng * 16 + m;
                float rgate = sigmoid_f(acc[ng][rg]);
                float zgate = sigmoid_f(acc[ng + NG / 2][rg]);
                int laddr = (((n >> 3) * 4 + (rw + 1)) * 35 + (1 + lcol)) * 8 + (n & 7);
                float h = b2f(sh[laddr]) + b2f(sl[laddr]);
                RHp[(long)psp * 32 + n] = packsplit(rgate * h);
                zbuf[(long)pxp * 32 + n] = zgate;
            }
    } else {
#pragma unroll
        for (int ng = 0; ng < NG; ++ng)
#pragma unroll
            for (int rg = 0; rg < 4; ++rg) {
                int lcol = m16 + q * 4 + rg;
                int psp  = (b * PH + prow + 1) * PH + (col0p + 1 + lcol);
                int pxp  = (b * HH + prow) * HH + (col0p + lcol);
                int n    = ng * 16 + m;
                float nv = tanh_f(acc[ng][rg]);
                float zz = zbuf[(long)pxp * 32 + n];
                long sidx = (long)psp * 64 + HB + n;
                float h = unpack2f(Sp[sidx]);
                Sp[sidx] = packsplit((1.0f - zz) * h + zz * nv);
            }
    }
#undef KSTEP
}

// ---- final: S ch32-63 (h1) -> d_out NCHW fp32 ----
__global__ void final_out(const unsigned int* __restrict__ Sp, float* __restrict__ out)
{
    int i = blockIdx.x * 256 + threadIdx.x;    // B*32*HW = 4194304
    if (i >= BB * 32 * HW) return;
    int pix = i & 16383;
    int t = i >> 14;
    int c = t & 31, b = t >> 5;
    int r = pix >> 7, cc = pix & 127;
    long ps = (long)(b * PH + r + 1) * PH + cc + 1;
    out[i] = unpack2f(Sp[ps * 64 + 32 + c]);
}

extern "C" void kernel_launch(void* const* d_in, const int* in_sizes, int n_in,
                              void* d_out, int out_size, void* d_ws, size_t ws_size,
                              hipStream_t stream)
{
    const float* seq = (const float*)d_in[0];
    const float* gw0 = (const float*)d_in[1];
    const float* gb0 = (const float*)d_in[2];
    const float* cw0 = (const float*)d_in[3];
    const float* cb0 = (const float*)d_in[4];
    const float* gw1 = (const float*)d_in[5];
    const float* gb1 = (const float*)d_in[6];
    const float* cw1 = (const float*)d_in[7];
    const float* cb1 = (const float*)d_in[8];
    float* out = (float*)d_out;

    const size_t NS  = (size_t)BB * PH * PH * 64;    // 8,652,800 u32
    const size_t NRH = (size_t)BB * PH * PH * 32;    // 4,326,400 u32
    const size_t NZ  = (size_t)BB * HH * HH * 32;    // 4,194,304 f32

    char* p = (char*)d_ws;
    unsigned int* Sp  = (unsigned int*)p; p += NS  * 4;
    unsigned int* RHp = (unsigned int*)p; p += NRH * 4;
    float* zbuf       = (float*)p;        p += NZ  * 4;
    unsigned short* WG0h = (unsigned short*)p; p += 20480 * 2;
    unsigned short* WG0l = (unsigned short*)p; p += 20480 * 2;
    unsigned short* WC0h = (unsigned short*)p; p += 10240 * 2;
    unsigned short* WC0l = (unsigned short*)p; p += 10240 * 2;
    unsigned short* WG1h = (unsigned short*)p; p += 36864 * 2;
    unsigned short* WG1l = (unsigned short*)p; p += 36864 * 2;
    unsigned short* WC1h = (unsigned short*)p; p += 18432 * 2;
    unsigned short* WC1l = (unsigned short*)p; p += 18432 * 2;

    // zero S (states + halo) and RH (halo), one contiguous span
    hipMemsetAsync(Sp, 0, (NS + NRH) * 4, stream);

    prep_w<<<(10 * 64 * 32 + 255) / 256, 256, 0, stream>>>(gw0, WG0h, WG0l, 64, 33, 10, 1);
    prep_w<<<(10 * 32 * 32 + 255) / 256, 256, 0, stream>>>(cw0, WC0h, WC0l, 32, 33, 10, 1);
    prep_w<<<(18 * 64 * 32 + 255) / 256, 256, 0, stream>>>(gw1, WG1h, WG1l, 64, 64, 18, 0);
    prep_w<<<(18 * 32 * 32 + 255) / 256, 256, 0, stream>>>(cw1, WC1h, WC1l, 32, 64, 18, 0);

    dim3 grid(256, BB), block(256);
    const long xbs = (long)TT * HW;
    for (int t = 0; t < TT; ++t) {
        const float* xt = seq + (long)t * HW;
        conv_mfma<0><<<grid, block, 0, stream>>>(Sp, RHp, xt, xbs, WG0h, WG0l, gb0, zbuf);
        conv_mfma<1><<<grid, block, 0, stream>>>(Sp, RHp, xt, xbs, WC0h, WC0l, cb0, zbuf);
        conv_mfma<2><<<grid, block, 0, stream>>>(Sp, RHp, xt, xbs, WG1h, WG1l, gb1, zbuf);
        conv_mfma<3><<<grid, block, 0, stream>>>(Sp, RHp, xt, xbs, WC1h, WC1l, cb1, zbuf);
    }
    final_out<<<(BB * 32 * HW + 255) / 256, 256, 0, stream>>>(Sp, out);
}

// Round 6
// 1298.347 us; speedup vs baseline: 2.4301x; 2.4301x over previous
//
#include <hip/hip_runtime.h>
#include <hip/hip_bf16.h>

// ConvGRU via fp16 MFMA implicit GEMM, LDS tap staging.
// States fp16 NHWC, 1-px zero halo: Sf[B][130][130][64] (ch0-31=h0,
// ch32-63=h1), RHf[B][130][130][32], z stored fp16.
// Conv = per-tap 16x16x32_f16 MFMAs, fp32 accumulate; single-term fp16
// (rel err 2^-11) -- measured fp32 floor is 4.9e-4, threshold 3.36e-3.
// Tile 4 rows x 32 cols per WG (4 waves; wave=row, 2 m-tiles), grid 1024.

#define HH 128
#define PH 130
#define HW 16384
#define BB 8
#define TT 16

typedef _Float16 f16x8 __attribute__((ext_vector_type(8)));
typedef float f32x4 __attribute__((ext_vector_type(4)));
typedef unsigned int u32x4 __attribute__((ext_vector_type(4)));

#define SLOT_SZ (4 * 6 * 35 * 8)   // 6720 ushorts = 13440 B (col stride 35)

__device__ __forceinline__ unsigned short f2h(float x){
    return __builtin_bit_cast(unsigned short, (_Float16)x);
}
__device__ __forceinline__ float h2f(unsigned short u){
    return (float)__builtin_bit_cast(_Float16, u);
}
__device__ __forceinline__ f16x8 ld_frag(const unsigned short* p){
    u32x4 v = *(const u32x4*)p;
    return __builtin_bit_cast(f16x8, v);
}
__device__ __forceinline__ f16x8 lds_frag(const unsigned short* slot, int q, int row, int col){
    u32x4 v = *(const u32x4*)(slot + ((q * 6 + row) * 35 + col) * 8);
    return __builtin_bit_cast(f16x8, v);
}
__device__ __forceinline__ float sigmoid_f(float a){ return 1.0f / (1.0f + __expf(-a)); }
__device__ __forceinline__ float tanh_f(float a){ float e2 = __expf(2.0f * a); return 1.0f - 2.0f / (e2 + 1.0f); }

// stage one fp16 32-ch plane tile (6 rows x 34 cols) into an LDS slot.
// LDS slot layout: [qblk 4][row 6][col 35(pad)][8ch].
__device__ __forceinline__ void stage_slot(unsigned short* slot,
    const unsigned short* __restrict__ g, int pch, int choff, int pbase)
{
    for (int c = threadIdx.x; c < 816; c += 256) {
        int qq = c & 3;
        int p  = c >> 2;
        int r  = p / 34, cc = p - r * 34;
        const unsigned short* ga = g + (long)(pbase + r * PH + cc) * pch + choff + qq * 8;
        u32x4 v = *(const u32x4*)ga;
        *(u32x4*)(slot + ((qq * 6 + r) * 35 + cc) * 8) = v;
    }
}

// stage raw x (unpadded fp32 image) tile with bounds-check into LDS
__device__ __forceinline__ void stage_x(float* xt, const float* __restrict__ x,
                                        int row0p, int col0p)
{
    for (int p = threadIdx.x; p < 204; p += 256) {
        int r = p / 34, cc = p - r * 34;
        int ir = row0p - 1 + r, ic = col0p - 1 + cc;
        float v = 0.0f;
        if (ir >= 0 && ir < HH && ic >= 0 && ic < HH) v = x[ir * HH + ic];
        xt[r * 35 + cc] = v;
    }
}

// ---- weight prep: [cout][cin_tot][9] fp32 -> [step][cout][32] fp16 ----
__global__ void prep_w(const float* __restrict__ w, unsigned short* __restrict__ wf,
                       int CO, int CIT, int NSTEP, int xmode)
{
    int idx = blockIdx.x * 256 + threadIdx.x;
    int total = NSTEP * CO * 32;
    if (idx >= total) return;
    int kk = idx & 31;
    int t  = idx >> 5;
    int co = t % CO;
    int s  = t / CO;
    float v = 0.0f;
    if (xmode && s == NSTEP - 1) {
        if (kk < 9) v = w[(co * CIT + 0) * 9 + kk];
    } else {
        int tap = s % 9;
        int cin = (s / 9) * 32 + kk + (xmode ? 1 : 0);
        v = w[(co * CIT + cin) * 9 + tap];
    }
    wf[idx] = f2h(v);
}

// ---- fused conv+epilogue. CONV: 0=gates0 1=cand0 2=gates1 3=cand1 ----
// WG = 256 thr (4 waves), tile 4 rows x 32 cols; wave = one row, 2 m-tiles.
template<int CONV>
__global__ __launch_bounds__(256, 4)
void conv_mfma(unsigned short* __restrict__ Sf, unsigned short* __restrict__ RHf,
               const float* __restrict__ xraw, long xbs,
               const unsigned short* __restrict__ Wf,
               const float* __restrict__ bias, unsigned short* __restrict__ zbuf)
{
    constexpr bool GATES = (CONV == 0 || CONV == 2);
    constexpr bool XMODE = (CONV < 2);
    constexpr int CO = GATES ? 64 : 32;
    constexpr int NG = CO / 16;
    constexpr int NSTEP = XMODE ? 10 : 18;
    constexpr int NSLOT = XMODE ? 1 : 2;
    constexpr int HB = XMODE ? 0 : 32;   // h channel base in Sf (h0 vs h1)

    __shared__ __align__(16) unsigned short lds[NSLOT][SLOT_SZ];
    __shared__ float xt[XMODE ? 210 : 1];

    const int b   = blockIdx.y;
    const int tc  = blockIdx.x & 3;     // 0..3   (32-col tiles)
    const int tr  = blockIdx.x >> 2;    // 0..31  (4-row tiles)
    const int row0p = tr * 4;           // halo origin, padded coords
    const int col0p = tc * 32;
    const int pbase = (b * PH + row0p) * PH + col0p;

    // staging: slot0 = tap-plane-1, slot1 = tap-plane-2
    if (CONV == 0)      stage_slot(lds[0], Sf, 64, 0, pbase);
    else if (CONV == 1) stage_slot(lds[0], RHf, 32, 0, pbase);
    else if (CONV == 2) { stage_slot(lds[0], Sf, 64, 0, pbase);
                          stage_slot(lds[1], Sf, 64, 32, pbase); }
    else                { stage_slot(lds[0], Sf, 64, 0, pbase);
                          stage_slot(lds[1], RHf, 32, 0, pbase); }
    if (XMODE) stage_x(xt, xraw + (long)b * xbs, row0p, col0p);
    __syncthreads();

    const int wv   = threadIdx.x >> 6;  // row within tile
    const int lane = threadIdx.x & 63;
    const int m    = lane & 15, q = lane >> 4;

    f32x4 acc[2][NG];
#pragma unroll
    for (int ng = 0; ng < NG; ++ng) {
        float bv = bias[ng * 16 + m];
#pragma unroll
        for (int mg = 0; mg < 2; ++mg) acc[mg][ng] = f32x4{bv, bv, bv, bv};
    }

#define KSTEP(S, SLOT, TAP)                                                     \
    {                                                                           \
        f16x8 A[2], B[NG];                                                      \
        const int rr = wv + (TAP) / 3, csh = (TAP) % 3;                         \
        _Pragma("unroll")                                                       \
        for (int mg = 0; mg < 2; ++mg)                                          \
            A[mg] = lds_frag(lds[SLOT], q, rr, mg * 16 + m + csh);              \
        _Pragma("unroll")                                                       \
        for (int ng = 0; ng < NG; ++ng)                                         \
            B[ng] = ld_frag(Wf + ((S) * CO + ng * 16 + m) * 32 + q * 8);        \
        _Pragma("unroll")                                                       \
        for (int mg = 0; mg < 2; ++mg)                                          \
            _Pragma("unroll")                                                   \
            for (int ng = 0; ng < NG; ++ng)                                     \
                acc[mg][ng] = __builtin_amdgcn_mfma_f32_16x16x32_f16(A[mg], B[ng], acc[mg][ng], 0, 0, 0); \
    }

#pragma unroll
    for (int s = 0; s < 9; ++s) KSTEP(s, 0, s)

    if (XMODE) {
        // im2col x step (s=9): A[m][k] = x tap k (k<9), else 0
        f16x8 A[2], B[NG];
#pragma unroll
        for (int mg = 0; mg < 2; ++mg) {
            f16x8 v;
#pragma unroll
            for (int j = 0; j < 8; ++j) {
                int k = q * 8 + j;
                float f = 0.0f;
                if (k < 9) f = xt[(wv + k / 3) * 35 + (mg * 16 + m + k % 3)];
                v[j] = (_Float16)f;
            }
            A[mg] = v;
        }
#pragma unroll
        for (int ng = 0; ng < NG; ++ng)
            B[ng] = ld_frag(Wf + (9 * CO + ng * 16 + m) * 32 + q * 8);
#pragma unroll
        for (int mg = 0; mg < 2; ++mg)
#pragma unroll
            for (int ng = 0; ng < NG; ++ng)
                acc[mg][ng] = __builtin_amdgcn_mfma_f32_16x16x32_f16(A[mg], B[ng], acc[mg][ng], 0, 0, 0);
    } else {
#pragma unroll
        for (int s = 9; s < 18; ++s) KSTEP(s, 1, s - 9)
    }

    // ---- epilogue. C layout: col(n)=lane&15, row(pixel)=q*4+reg ----
    const int prow = row0p + wv;   // image row of this wave's pixels
    if (GATES) {
        // h for r*h: conv0 -> h0 (Sf ch 0-31), conv2 -> h1 (Sf ch 32-63)
        constexpr int HRD = (CONV == 0) ? 0 : 32;
#pragma unroll
        for (int mg = 0; mg < 2; ++mg)
#pragma unroll
            for (int ng = 0; ng < NG / 2; ++ng)
#pragma unroll
                for (int rg = 0; rg < 4; ++rg) {
                    int lcol = mg * 16 + q * 4 + rg;               // 0..31
                    long psp = (long)(b * PH + prow + 1) * PH + (col0p + 1 + lcol);
                    long pxp = (long)(b * HH + prow) * HH + (col0p + lcol);
                    int n    = ng * 16 + m;
                    float rgate = sigmoid_f(acc[mg][ng][rg]);
                    float zgate = sigmoid_f(acc[mg][ng + NG / 2][rg]);
                    float h = h2f(Sf[psp * 64 + HRD + n]);
                    RHf[psp * 32 + n] = f2h(rgate * h);
                    zbuf[pxp * 32 + n] = f2h(zgate);
                }
    } else {
#pragma unroll
        for (int mg = 0; mg < 2; ++mg)
#pragma unroll
            for (int ng = 0; ng < NG; ++ng)
#pragma unroll
                for (int rg = 0; rg < 4; ++rg) {
                    int lcol = mg * 16 + q * 4 + rg;
                    long psp = (long)(b * PH + prow + 1) * PH + (col0p + 1 + lcol);
                    long pxp = (long)(b * HH + prow) * HH + (col0p + lcol);
                    int n    = ng * 16 + m;
                    float nv = tanh_f(acc[mg][ng][rg]);
                    float zz = h2f(zbuf[pxp * 32 + n]);
                    long sidx = psp * 64 + HB + n;
                    float h = h2f(Sf[sidx]);
                    Sf[sidx] = f2h((1.0f - zz) * h + zz * nv);
                }
    }
#undef KSTEP
}

// ---- final: Sf ch32-63 (h1) -> d_out NCHW fp32 ----
__global__ void final_out(const unsigned short* __restrict__ Sf, float* __restrict__ out)
{
    int i = blockIdx.x * 256 + threadIdx.x;    // B*32*HW = 4194304
    if (i >= BB * 32 * HW) return;
    int pix = i & 16383;
    int t = i >> 14;
    int c = t & 31, b = t >> 5;
    int r = pix >> 7, cc = pix & 127;
    long ps = (long)(b * PH + r + 1) * PH + cc + 1;
    out[i] = h2f(Sf[ps * 64 + 32 + c]);
}

extern "C" void kernel_launch(void* const* d_in, const int* in_sizes, int n_in,
                              void* d_out, int out_size, void* d_ws, size_t ws_size,
                              hipStream_t stream)
{
    const float* seq = (const float*)d_in[0];
    const float* gw0 = (const float*)d_in[1];
    const float* gb0 = (const float*)d_in[2];
    const float* cw0 = (const float*)d_in[3];
    const float* cb0 = (const float*)d_in[4];
    const float* gw1 = (const float*)d_in[5];
    const float* gb1 = (const float*)d_in[6];
    const float* cw1 = (const float*)d_in[7];
    const float* cb1 = (const float*)d_in[8];
    float* out = (float*)d_out;

    const size_t NS  = (size_t)BB * PH * PH * 64;    // 8,652,800 fp16
    const size_t NRH = (size_t)BB * PH * PH * 32;    // 4,326,400 fp16
    const size_t NZ  = (size_t)BB * HH * HH * 32;    // 4,194,304 fp16

    char* p = (char*)d_ws;
    unsigned short* Sf  = (unsigned short*)p; p += NS  * 2;
    unsigned short* RHf = (unsigned short*)p; p += NRH * 2;
    unsigned short* zbuf= (unsigned short*)p; p += NZ  * 2;
    unsigned short* WG0 = (unsigned short*)p; p += 20480 * 2;
    unsigned short* WC0 = (unsigned short*)p; p += 10240 * 2;
    unsigned short* WG1 = (unsigned short*)p; p += 36864 * 2;
    unsigned short* WC1 = (unsigned short*)p; p += 18432 * 2;

    // zero S (states + halo) and RH (halo), one contiguous span
    hipMemsetAsync(Sf, 0, (NS + NRH) * 2, stream);

    prep_w<<<(10 * 64 * 32 + 255) / 256, 256, 0, stream>>>(gw0, WG0, 64, 33, 10, 1);
    prep_w<<<(10 * 32 * 32 + 255) / 256, 256, 0, stream>>>(cw0, WC0, 32, 33, 10, 1);
    prep_w<<<(18 * 64 * 32 + 255) / 256, 256, 0, stream>>>(gw1, WG1, 64, 64, 18, 0);
    prep_w<<<(18 * 32 * 32 + 255) / 256, 256, 0, stream>>>(cw1, WC1, 32, 64, 18, 0);

    dim3 grid(128, BB), block(256);
    const long xbs = (long)TT * HW;
    for (int t = 0; t < TT; ++t) {
        const float* xt = seq + (long)t * HW;
        conv_mfma<0><<<grid, block, 0, stream>>>(Sf, RHf, xt, xbs, WG0, gb0, zbuf);
        conv_mfma<1><<<grid, block, 0, stream>>>(Sf, RHf, xt, xbs, WC0, cb0, zbuf);
        conv_mfma<2><<<grid, block, 0, stream>>>(Sf, RHf, xt, xbs, WG1, gb1, zbuf);
        conv_mfma<3><<<grid, block, 0, stream>>>(Sf, RHf, xt, xbs, WC1, cb1, zbuf);
    }
    final_out<<<(BB * 32 * HW + 255) / 256, 256, 0, stream>>>(Sf, out);
}

// Round 7
// 1274.733 us; speedup vs baseline: 2.4751x; 1.0185x over previous
//
#include <hip/hip_runtime.h>
#include <hip/hip_bf16.h>

// ConvGRU via fp16 MFMA implicit GEMM, DMA (global_load_lds) tap staging.
// States fp16 NHWC in SEPARATE planes, 1-px zero halo:
//   S0[B][130][130][32]=h0, S1[...]=h1, RH[...]=r*h, zbuf fp16.
// LDS slot = linear [pixel 6x34][32ch] fp16 (13,312B incl 256B clamp pad):
//   - DMA-compatible (lane i -> base + i*16B)
//   - K-loop ds_read_b128 across a wave = one contiguous 1KB region: 0 conflicts
// Conv = per-tap 16x16x32_f16 MFMAs, fp32 accumulate (abs err floor ~1e-3,
// threshold 3.36e-3). Tile 4 rows x 32 cols per WG (4 waves), grid 1024.

#define HH 128
#define PH 130
#define HW 16384
#define BB 8
#define TT 16

typedef _Float16 f16x8 __attribute__((ext_vector_type(8)));
typedef float f32x4 __attribute__((ext_vector_type(4)));
typedef unsigned int u32x4 __attribute__((ext_vector_type(4)));

#define SLOT_SZ 6656   // ushorts: 204px*32ch = 6528 + 128 clamp slack (13312 B)

__device__ __forceinline__ unsigned short f2h(float x){
    return __builtin_bit_cast(unsigned short, (_Float16)x);
}
__device__ __forceinline__ float h2f(unsigned short u){
    return (float)__builtin_bit_cast(_Float16, u);
}
__device__ __forceinline__ f16x8 ld_frag(const unsigned short* p){
    u32x4 v = *(const u32x4*)p;
    return __builtin_bit_cast(f16x8, v);
}
// fragment read from linear slot: pixel (row,col) of 6x34, ch octet q
__device__ __forceinline__ f16x8 lds_frag(const unsigned short* slot, int q, int row, int col){
    u32x4 v = *(const u32x4*)(slot + ((row * 34 + col) * 32 + q * 8));
    return __builtin_bit_cast(f16x8, v);
}
__device__ __forceinline__ float sigmoid_f(float a){ return 1.0f / (1.0f + __expf(-a)); }
__device__ __forceinline__ float tanh_f(float a){ float e2 = __expf(2.0f * a); return 1.0f - 2.0f / (e2 + 1.0f); }

// ---- async DMA staging: one fp16 32-ch plane tile (6 rows x 34 cols) ----
// chunk c (16B, 4 per pixel): lane l of iter k handles chunk 64k+l.
// LDS dest = slot + k*512 ushorts + lane*8  (HW: uniform base + lane*16B).
__device__ __forceinline__ void stage_dma(unsigned short* slot,
    const unsigned short* __restrict__ g, int pbase)
{
    const int wv = threadIdx.x >> 6, lane = threadIdx.x & 63;
    for (int k = wv; k < 13; k += 4) {
        int chunk = k * 64 + lane;
        chunk = chunk > 815 ? 815 : chunk;      // dup tail into slack region
        int pix = chunk >> 2, part = chunk & 3;
        int r = pix / 34, cc = pix - r * 34;
        const unsigned short* ga = g + ((long)(pbase + r * PH + cc) * 32 + part * 8);
        __builtin_amdgcn_global_load_lds(
            (const __attribute__((address_space(1))) unsigned int*)ga,
            (__attribute__((address_space(3))) unsigned int*)(slot + k * 512),
            16, 0, 0);
    }
}

// stage raw x (unpadded fp32 image) tile with bounds-check into LDS
__device__ __forceinline__ void stage_x(float* xt, const float* __restrict__ x,
                                        int row0p, int col0p)
{
    for (int p = threadIdx.x; p < 204; p += 256) {
        int r = p / 34, cc = p - r * 34;
        int ir = row0p - 1 + r, ic = col0p - 1 + cc;
        float v = 0.0f;
        if (ir >= 0 && ir < HH && ic >= 0 && ic < HH) v = x[ir * HH + ic];
        xt[r * 35 + cc] = v;
    }
}

// ---- weight prep: [cout][cin_tot][9] fp32 -> [step][cout][32] fp16 ----
__global__ void prep_w(const float* __restrict__ w, unsigned short* __restrict__ wf,
                       int CO, int CIT, int NSTEP, int xmode)
{
    int idx = blockIdx.x * 256 + threadIdx.x;
    int total = NSTEP * CO * 32;
    if (idx >= total) return;
    int kk = idx & 31;
    int t  = idx >> 5;
    int co = t % CO;
    int s  = t / CO;
    float v = 0.0f;
    if (xmode && s == NSTEP - 1) {
        if (kk < 9) v = w[(co * CIT + 0) * 9 + kk];
    } else {
        int tap = s % 9;
        int cin = (s / 9) * 32 + kk + (xmode ? 1 : 0);
        v = w[(co * CIT + cin) * 9 + tap];
    }
    wf[idx] = f2h(v);
}

// ---- fused conv+epilogue. CONV: 0=gates0 1=cand0 2=gates1 3=cand1 ----
// WG = 256 thr (4 waves), tile 4 rows x 32 cols; wave = one row, 2 m-tiles.
template<int CONV>
__global__ __launch_bounds__(256, 4)
void conv_mfma(unsigned short* __restrict__ S0, unsigned short* __restrict__ S1,
               unsigned short* __restrict__ RH,
               const float* __restrict__ xraw, long xbs,
               const unsigned short* __restrict__ Wf,
               const float* __restrict__ bias, unsigned short* __restrict__ zbuf)
{
    constexpr bool GATES = (CONV == 0 || CONV == 2);
    constexpr bool XMODE = (CONV < 2);
    constexpr int CO = GATES ? 64 : 32;
    constexpr int NG = CO / 16;
    constexpr int NSLOT = XMODE ? 1 : 2;

    __shared__ __align__(16) unsigned short lds[NSLOT][SLOT_SZ];
    __shared__ float xt[XMODE ? 210 : 1];

    const int b   = blockIdx.y;
    const int tc  = blockIdx.x & 3;     // 0..3   (32-col tiles)
    const int tr  = blockIdx.x >> 2;    // 0..31  (4-row tiles)
    const int row0p = tr * 4;           // halo origin, padded coords
    const int col0p = tc * 32;
    const int pbase = (b * PH + row0p) * PH + col0p;

    // async staging (all loads in flight; drained by barrier's vmcnt(0))
    if (CONV == 0)      stage_dma(lds[0], S0, pbase);
    else if (CONV == 1) stage_dma(lds[0], RH, pbase);
    else if (CONV == 2) { stage_dma(lds[0], S0, pbase); stage_dma(lds[1], S1, pbase); }
    else                { stage_dma(lds[0], S0, pbase); stage_dma(lds[1], RH, pbase); }
    if (XMODE) stage_x(xt, xraw + (long)b * xbs, row0p, col0p);
    __syncthreads();

    const int wv   = threadIdx.x >> 6;  // row within tile
    const int lane = threadIdx.x & 63;
    const int m    = lane & 15, q = lane >> 4;

    f32x4 acc[2][NG];
#pragma unroll
    for (int ng = 0; ng < NG; ++ng) {
        float bv = bias[ng * 16 + m];
#pragma unroll
        for (int mg = 0; mg < 2; ++mg) acc[mg][ng] = f32x4{bv, bv, bv, bv};
    }

#define KSTEP(S, SLOT, TAP)                                                     \
    {                                                                           \
        f16x8 A[2], B[NG];                                                      \
        const int rr = wv + (TAP) / 3, csh = (TAP) % 3;                         \
        _Pragma("unroll")                                                       \
        for (int mg = 0; mg < 2; ++mg)                                          \
            A[mg] = lds_frag(lds[SLOT], q, rr, mg * 16 + m + csh);              \
        _Pragma("unroll")                                                       \
        for (int ng = 0; ng < NG; ++ng)                                         \
            B[ng] = ld_frag(Wf + ((S) * CO + ng * 16 + m) * 32 + q * 8);        \
        _Pragma("unroll")                                                       \
        for (int mg = 0; mg < 2; ++mg)                                          \
            _Pragma("unroll")                                                   \
            for (int ng = 0; ng < NG; ++ng)                                     \
                acc[mg][ng] = __builtin_amdgcn_mfma_f32_16x16x32_f16(A[mg], B[ng], acc[mg][ng], 0, 0, 0); \
    }

#pragma unroll
    for (int s = 0; s < 9; ++s) KSTEP(s, 0, s)

    if (XMODE) {
        // im2col x step (s=9): A[m][k] = x tap k (k<9), else 0
        f16x8 A[2], B[NG];
#pragma unroll
        for (int mg = 0; mg < 2; ++mg) {
            f16x8 v;
#pragma unroll
            for (int j = 0; j < 8; ++j) {
                int k = q * 8 + j;
                float f = 0.0f;
                if (k < 9) f = xt[(wv + k / 3) * 35 + (mg * 16 + m + k % 3)];
                v[j] = (_Float16)f;
            }
            A[mg] = v;
        }
#pragma unroll
        for (int ng = 0; ng < NG; ++ng)
            B[ng] = ld_frag(Wf + (9 * CO + ng * 16 + m) * 32 + q * 8);
#pragma unroll
        for (int mg = 0; mg < 2; ++mg)
#pragma unroll
            for (int ng = 0; ng < NG; ++ng)
                acc[mg][ng] = __builtin_amdgcn_mfma_f32_16x16x32_f16(A[mg], B[ng], acc[mg][ng], 0, 0, 0);
    } else {
#pragma unroll
        for (int s = 9; s < 18; ++s) KSTEP(s, 1, s - 9)
    }

    // ---- epilogue. C layout: col(n)=lane&15, row(pixel)=q*4+reg ----
    const int prow = row0p + wv;   // image row of this wave's pixels
    if (GATES) {
        // h for r*h from LDS: conv0 -> h0 = slot0; conv2 -> h1 = slot1
        constexpr int HSLOT = (CONV == 0) ? 0 : 1;
#pragma unroll
        for (int mg = 0; mg < 2; ++mg)
#pragma unroll
            for (int ng = 0; ng < NG / 2; ++ng)
#pragma unroll
                for (int rg = 0; rg < 4; ++rg) {
                    int lcol = mg * 16 + q * 4 + rg;               // 0..31
                    long psp = (long)(b * PH + prow + 1) * PH + (col0p + 1 + lcol);
                    long pxp = (long)(b * HH + prow) * HH + (col0p + lcol);
                    int n    = ng * 16 + m;
                    float rgate = sigmoid_f(acc[mg][ng][rg]);
                    float zgate = sigmoid_f(acc[mg][ng + NG / 2][rg]);
                    float h = h2f(lds[HSLOT][((wv + 1) * 34 + 1 + lcol) * 32 + n]);
                    RH[psp * 32 + n] = f2h(rgate * h);
                    zbuf[pxp * 32 + n] = f2h(zgate);
                }
    } else {
        unsigned short* Sout = XMODE ? S0 : S1;
#pragma unroll
        for (int mg = 0; mg < 2; ++mg)
#pragma unroll
            for (int ng = 0; ng < NG; ++ng)
#pragma unroll
                for (int rg = 0; rg < 4; ++rg) {
                    int lcol = mg * 16 + q * 4 + rg;
                    long psp = (long)(b * PH + prow + 1) * PH + (col0p + 1 + lcol);
                    long pxp = (long)(b * HH + prow) * HH + (col0p + lcol);
                    int n    = ng * 16 + m;
                    float nv = tanh_f(acc[mg][ng][rg]);
                    float zz = h2f(zbuf[pxp * 32 + n]);
                    long sidx = psp * 32 + n;
                    float h = h2f(Sout[sidx]);
                    Sout[sidx] = f2h((1.0f - zz) * h + zz * nv);
                }
    }
#undef KSTEP
}

// ---- final: S1 (h1) -> d_out NCHW fp32 ----
__global__ void final_out(const unsigned short* __restrict__ S1, float* __restrict__ out)
{
    int i = blockIdx.x * 256 + threadIdx.x;    // B*32*HW = 4194304
    if (i >= BB * 32 * HW) return;
    int pix = i & 16383;
    int t = i >> 14;
    int c = t & 31, b = t >> 5;
    int r = pix >> 7, cc = pix & 127;
    long ps = (long)(b * PH + r + 1) * PH + cc + 1;
    out[i] = h2f(S1[ps * 32 + c]);
}

extern "C" void kernel_launch(void* const* d_in, const int* in_sizes, int n_in,
                              void* d_out, int out_size, void* d_ws, size_t ws_size,
                              hipStream_t stream)
{
    const float* seq = (const float*)d_in[0];
    const float* gw0 = (const float*)d_in[1];
    const float* gb0 = (const float*)d_in[2];
    const float* cw0 = (const float*)d_in[3];
    const float* cb0 = (const float*)d_in[4];
    const float* gw1 = (const float*)d_in[5];
    const float* gb1 = (const float*)d_in[6];
    const float* cw1 = (const float*)d_in[7];
    const float* cb1 = (const float*)d_in[8];
    float* out = (float*)d_out;

    const size_t NSP = (size_t)BB * PH * PH * 32;    // 4,326,400 fp16 per plane
    const size_t NZ  = (size_t)BB * HH * HH * 32;    // 4,194,304 fp16

    char* p = (char*)d_ws;
    unsigned short* S0  = (unsigned short*)p; p += NSP * 2;
    unsigned short* S1  = (unsigned short*)p; p += NSP * 2;
    unsigned short* RH  = (unsigned short*)p; p += NSP * 2;
    unsigned short* zbuf= (unsigned short*)p; p += NZ  * 2;
    unsigned short* WG0 = (unsigned short*)p; p += 20480 * 2;
    unsigned short* WC0 = (unsigned short*)p; p += 10240 * 2;
    unsigned short* WG1 = (unsigned short*)p; p += 36864 * 2;
    unsigned short* WC1 = (unsigned short*)p; p += 18432 * 2;

    // zero S0,S1 (states + halo) and RH (halo), one contiguous span
    hipMemsetAsync(S0, 0, 3 * NSP * 2, stream);

    prep_w<<<(10 * 64 * 32 + 255) / 256, 256, 0, stream>>>(gw0, WG0, 64, 33, 10, 1);
    prep_w<<<(10 * 32 * 32 + 255) / 256, 256, 0, stream>>>(cw0, WC0, 32, 33, 10, 1);
    prep_w<<<(18 * 64 * 32 + 255) / 256, 256, 0, stream>>>(gw1, WG1, 64, 64, 18, 0);
    prep_w<<<(18 * 32 * 32 + 255) / 256, 256, 0, stream>>>(cw1, WC1, 32, 64, 18, 0);

    dim3 grid(128, BB), block(256);
    const long xbs = (long)TT * HW;
    for (int t = 0; t < TT; ++t) {
        const float* xt = seq + (long)t * HW;
        conv_mfma<0><<<grid, block, 0, stream>>>(S0, S1, RH, xt, xbs, WG0, gb0, zbuf);
        conv_mfma<1><<<grid, block, 0, stream>>>(S0, S1, RH, xt, xbs, WC0, cb0, zbuf);
        conv_mfma<2><<<grid, block, 0, stream>>>(S0, S1, RH, xt, xbs, WG1, gb1, zbuf);
        conv_mfma<3><<<grid, block, 0, stream>>>(S0, S1, RH, xt, xbs, WC1, cb1, zbuf);
    }
    final_out<<<(BB * 32 * HW + 255) / 256, 256, 0, stream>>>(S1, out);
}